// Round 1
// baseline (325.516 us; speedup 1.0000x reference)
//
#include <hip/hip_runtime.h>
#include <stdint.h>

#define BB 2
#define SS 2048
#define MM 2048
#define NQ 16
#define NKV 4
#define HH 128

typedef __attribute__((ext_vector_type(4))) float f32x4;
typedef _Float16 f16x8 __attribute__((ext_vector_type(8)));
typedef _Float16 f16x4 __attribute__((ext_vector_type(4)));

__device__ __forceinline__ void async_copy16(const _Float16* g, _Float16* l) {
  __builtin_amdgcn_global_load_lds(
      (__attribute__((address_space(1))) void*)g,
      (__attribute__((address_space(3))) void*)l, 16, 0, 0);
}

// ---------------- fp32 -> fp16 convert (vectorized) ----------------
__global__ __launch_bounds__(256) void k_f32_to_f16(const float* __restrict__ in,
                                                    _Float16* __restrict__ out, int n4) {
  int i = blockIdx.x * 256 + threadIdx.x;
  if (i >= n4) return;
  float4 v = ((const float4*)in)[i];
  f16x4 o = { (_Float16)v.x, (_Float16)v.y, (_Float16)v.z, (_Float16)v.w };
  ((f16x4*)out)[i] = o;
}

// ------------- tiled transpose: in[K][N] f32 -> out[(n+n_off)][k] f16 -------------
__global__ __launch_bounds__(256) void k_transpose_f32_f16(
    const float* __restrict__ in, _Float16* __restrict__ out,
    int N_in, int n_off, int ldout) {
  __shared__ float tile[32][33];
  const int k0 = blockIdx.x * 32;
  const int n0 = blockIdx.y * 32;
  const int tx = threadIdx.x & 31;
  const int ty = threadIdx.x >> 5;
  #pragma unroll
  for (int r = ty; r < 32; r += 8)
    tile[r][tx] = in[(size_t)(k0 + r) * N_in + n0 + tx];
  __syncthreads();
  #pragma unroll
  for (int r = ty; r < 32; r += 8)
    out[(size_t)(n0 + r + n_off) * ldout + k0 + tx] = (_Float16)tile[tx][r];
}

// ---------------- 128x128 MFMA GEMM: C[M][N] = A[M][K] * Bt[N][K]^T ----------------
template <bool F16OUT>
__global__ __launch_bounds__(256) void k_gemm(
    const _Float16* __restrict__ A, const _Float16* __restrict__ Bt,
    void* __restrict__ Cout, int Mrows, int N, int K) {
  __shared__ _Float16 As[128 * 32];
  __shared__ _Float16 Bs[128 * 32];
  const int bm = blockIdx.x * 128;
  const int bn = blockIdx.y * 128;
  const int w = threadIdx.x >> 6;
  const int l = threadIdx.x & 63;
  const int lg = l >> 4, lr = l & 15;
  const int wr = w >> 1, wc = w & 1;

  f32x4 acc[4][4] = {};

  const _Float16* gA = A + (size_t)(bm + w * 32 + (l >> 2)) * K + (l & 3) * 8;
  const _Float16* gB = Bt + (size_t)(bn + w * 32 + (l >> 2)) * K + (l & 3) * 8;
  _Float16* lA = As + w * 32 * 32;  // wave-uniform LDS base; HW adds lane*16B
  _Float16* lB = Bs + w * 32 * 32;
  const size_t g16 = (size_t)16 * K;

  for (int k0 = 0; k0 < K; k0 += 32) {
    async_copy16(gA, lA);
    async_copy16(gA + g16, lA + 16 * 32);
    async_copy16(gB, lB);
    async_copy16(gB + g16, lB + 16 * 32);
    gA += 32; gB += 32;
    __syncthreads();
    f16x8 af[4], bfr[4];
    #pragma unroll
    for (int mt = 0; mt < 4; mt++)
      af[mt] = *(const f16x8*)(As + (wr * 64 + mt * 16 + lr) * 32 + lg * 8);
    #pragma unroll
    for (int nt = 0; nt < 4; nt++)
      bfr[nt] = *(const f16x8*)(Bs + (wc * 64 + nt * 16 + lr) * 32 + lg * 8);
    #pragma unroll
    for (int mt = 0; mt < 4; mt++)
      #pragma unroll
      for (int nt = 0; nt < 4; nt++)
        acc[mt][nt] = __builtin_amdgcn_mfma_f32_16x16x32_f16(af[mt], bfr[nt], acc[mt][nt], 0, 0, 0);
    __syncthreads();
  }
  #pragma unroll
  for (int mt = 0; mt < 4; mt++) {
    #pragma unroll
    for (int i = 0; i < 4; i++) {
      const int row = bm + wr * 64 + mt * 16 + lg * 4 + i;
      #pragma unroll
      for (int nt = 0; nt < 4; nt++) {
        const int col = bn + wc * 64 + nt * 16 + lr;
        if (F16OUT)
          ((_Float16*)Cout)[(size_t)row * N + col] = (_Float16)acc[mt][nt][i];
        else
          ((float*)Cout)[(size_t)row * N + col] = acc[mt][nt][i];
      }
    }
  }
}

// ---------------- fused RMSNorm + RoPE + scatter ----------------
// qkv: [B*S][3072] f16 (cols: q heads 0..15, k heads 16..19, v heads 20..23)
__global__ __launch_bounds__(256) void k_normrope(
    const _Float16* __restrict__ qkv,
    const float* __restrict__ q_scale, const float* __restrict__ k_scale,
    _Float16* __restrict__ Qr, _Float16* __restrict__ Kr, _Float16* __restrict__ Vr) {
  const int row = blockIdx.x;          // b*S + s
  const int b = row >> 11;
  const int s = row & 2047;
  const int hh = blockIdx.y * 4 + (threadIdx.x >> 6);
  const int l = threadIdx.x & 63;
  const _Float16* src = qkv + (size_t)row * 3072 + hh * 128 + l * 2;
  float x0 = (float)src[0];
  float x1 = (float)src[1];
  if (hh < 20) {
    float ssum = x0 * x0 + x1 * x1;
    #pragma unroll
    for (int d = 1; d < 64; d <<= 1) ssum += __shfl_xor(ssum, d);
    const float rstd = rsqrtf(ssum * (1.f / 128.f) + 1e-6f);
    const float* scl = (hh < 16) ? q_scale : k_scale;
    x0 *= rstd * scl[2 * l];
    x1 *= rstd * scl[2 * l + 1];
    const float y0 = __shfl_xor(x0, 32);
    const float y1 = __shfl_xor(x1, 32);
    const int j0 = (2 * l) & 63;
    const float kLog = 0.20762050593046014f;  // log2(10000)/64
    const float f0 = (float)s * exp2f(-(float)j0 * kLog);
    const float f1 = (float)s * exp2f(-(float)(j0 + 1) * kLog);
    const float c0 = cosf(f0), s0 = sinf(f0);
    const float c1 = cosf(f1), s1 = sinf(f1);
    float r0, r1;
    if (l < 32) { r0 = x0 * c0 - y0 * s0; r1 = x1 * c1 - y1 * s1; }
    else        { r0 = x0 * c0 + y0 * s0; r1 = x1 * c1 + y1 * s1; }
    if (hh < 16) {
      _Float16* dst = Qr + ((size_t)(b * NQ + hh) * SS + s) * HH + 2 * l;
      dst[0] = (_Float16)r0; dst[1] = (_Float16)r1;
    } else {
      _Float16* dst = Kr + ((size_t)(b * NKV + (hh - 16)) * SS + s) * HH + 2 * l;
      dst[0] = (_Float16)r0; dst[1] = (_Float16)r1;
    }
  } else {
    _Float16* dst = Vr + ((size_t)(b * NKV + (hh - 20)) * SS + s) * HH + 2 * l;
    dst[0] = src[0]; dst[1] = src[1];
  }
}

// ---------------- causal GQA flash attention ----------------
// Qr: [B][NQ][S][H], Kr/Vr: [B][NKV][S][H], Ao: [B][S][NQ][H]
__global__ __launch_bounds__(256) void k_attn(
    const _Float16* __restrict__ Qr, const _Float16* __restrict__ Kr,
    const _Float16* __restrict__ Vr, _Float16* __restrict__ Ao) {
  __shared__ _Float16 Ks[64][136];   // row-major K tile, padded (2-way max)
  __shared__ _Float16 Vt[128][72];   // V transposed [h][kv], XOR-swizzled kv
  __shared__ _Float16 Ps[4][16][72]; // per-wave P tile

  const int bu = blockIdx.x;
  const int b = bu >> 4, u = bu & 15;
  const int kvh = u >> 2;
  const int q0 = blockIdx.y * 64;
  const int w = threadIdx.x >> 6;
  const int l = threadIdx.x & 63;
  const int lg = l >> 4, lr = l & 15;
  const float inv_norm = 0.08838834764831845f;  // 1/sqrt(128)

  f16x8 qf[4];
  {
    const _Float16* qp = Qr + ((size_t)(b * NQ + u) * SS + q0 + w * 16 + lr) * HH + lg * 8;
    #pragma unroll
    for (int hs = 0; hs < 4; hs++) qf[hs] = *(const f16x8*)(qp + hs * 32);
  }

  f32x4 acc[8] = {};
  float mrow[4], lrow[4];
  #pragma unroll
  for (int i = 0; i < 4; i++) { mrow[i] = -1e30f; lrow[i] = 0.f; }

  const int ntiles = blockIdx.y + 1;
  const _Float16* Kbase = Kr + (size_t)(b * NKV + kvh) * SS * HH;
  const _Float16* Vbase = Vr + (size_t)(b * NKV + kvh) * SS * HH;

  for (int kt = 0; kt < ntiles; kt++) {
    const int kv0 = kt * 64;
    __syncthreads();  // previous tile fully consumed
    #pragma unroll
    for (int c = 0; c < 4; c++) {
      const int lin = c * 256 + threadIdx.x;
      const int r = lin >> 4, col = lin & 15;
      f16x8 kvv = *(const f16x8*)(Kbase + (size_t)(kv0 + r) * HH + col * 8);
      *(f16x8*)(&Ks[r][col * 8]) = kvv;
      f16x8 vv = *(const f16x8*)(Vbase + (size_t)(kv0 + r) * HH + col * 8);
      const int rsw = r ^ ((col & 7) << 3);
      #pragma unroll
      for (int j = 0; j < 8; j++) Vt[col * 8 + j][rsw] = vv[j];
    }
    __syncthreads();

    // QK^T
    f32x4 sc[4] = {};
    #pragma unroll
    for (int hs = 0; hs < 4; hs++)
      #pragma unroll
      for (int nt = 0; nt < 4; nt++) {
        f16x8 kf = *(const f16x8*)(&Ks[nt * 16 + lr][hs * 32 + lg * 8]);
        sc[nt] = __builtin_amdgcn_mfma_f32_16x16x32_f16(qf[hs], kf, sc[nt], 0, 0, 0);
      }

    // mask + scale + online softmax (C layout: row q = lg*4+i, col k = lr)
    float p[4][4], tmax[4];
    const int qa_base = q0 + w * 16 + lg * 4;
    #pragma unroll
    for (int i = 0; i < 4; i++) tmax[i] = -1e30f;
    #pragma unroll
    for (int nt = 0; nt < 4; nt++) {
      const int ka = kv0 + nt * 16 + lr;
      #pragma unroll
      for (int i = 0; i < 4; i++) {
        float sv = sc[nt][i] * inv_norm;
        if (ka > qa_base + i) sv = -1e9f;
        p[nt][i] = sv;
        tmax[i] = fmaxf(tmax[i], sv);
      }
    }
    #pragma unroll
    for (int i = 0; i < 4; i++)
      #pragma unroll
      for (int d = 1; d < 16; d <<= 1)
        tmax[i] = fmaxf(tmax[i], __shfl_xor(tmax[i], d));

    float corr[4], psum[4];
    #pragma unroll
    for (int i = 0; i < 4; i++) {
      const float mnew = fmaxf(mrow[i], tmax[i]);
      corr[i] = __expf(mrow[i] - mnew);
      mrow[i] = mnew;
      float acc_s = 0.f;
      #pragma unroll
      for (int nt = 0; nt < 4; nt++) {
        const float e = __expf(p[nt][i] - mnew);
        p[nt][i] = e;
        acc_s += e;
      }
      psum[i] = acc_s;
    }
    #pragma unroll
    for (int i = 0; i < 4; i++) {
      #pragma unroll
      for (int d = 1; d < 16; d <<= 1) psum[i] += __shfl_xor(psum[i], d);
      lrow[i] = lrow[i] * corr[i] + psum[i];
    }
    #pragma unroll
    for (int ht = 0; ht < 8; ht++)
      #pragma unroll
      for (int i = 0; i < 4; i++) acc[ht][i] *= corr[i];

    // P -> wave-private LDS (bf-free fp16), then PV
    #pragma unroll
    for (int nt = 0; nt < 4; nt++)
      #pragma unroll
      for (int i = 0; i < 4; i++)
        Ps[w][lg * 4 + i][nt * 16 + lr] = (_Float16)p[nt][i];

    #pragma unroll
    for (int ht = 0; ht < 8; ht++) {
      const int h_ = ht * 16 + lr;
      #pragma unroll
      for (int ks = 0; ks < 2; ks++) {
        f16x8 pf = *(const f16x8*)(&Ps[w][lr][ks * 32 + lg * 8]);
        f16x8 vf = *(const f16x8*)(&Vt[h_][(ks * 32 + lg * 8) ^ (((h_ >> 3) & 7) << 3)]);
        acc[ht] = __builtin_amdgcn_mfma_f32_16x16x32_f16(pf, vf, acc[ht], 0, 0, 0);
      }
    }
  }

  float inv[4];
  #pragma unroll
  for (int i = 0; i < 4; i++) inv[i] = 1.f / lrow[i];
  #pragma unroll
  for (int ht = 0; ht < 8; ht++)
    #pragma unroll
    for (int i = 0; i < 4; i++) {
      const int qa = q0 + w * 16 + lg * 4 + i;
      Ao[((size_t)(b * SS + qa) * NQ + u) * HH + ht * 16 + lr] = (_Float16)(acc[ht][i] * inv[i]);
    }
}

// ---------------- launcher ----------------
extern "C" void kernel_launch(void* const* d_in, const int* in_sizes, int n_in,
                              void* d_out, int out_size, void* d_ws, size_t ws_size,
                              hipStream_t stream) {
  const float* hidden = (const float*)d_in[0];
  // d_in[1] = attention_mask (causal tril) — structure applied directly
  const float* Wq = (const float*)d_in[2];
  const float* Wk = (const float*)d_in[3];
  const float* Wv = (const float*)d_in[4];
  const float* Wo = (const float*)d_in[5];
  const float* q_scale = (const float*)d_in[6];
  const float* k_scale = (const float*)d_in[7];

  char* ws = (char*)d_ws;
  _Float16* Xb    = (_Float16*)(ws);               // 4096x2048      16.78 MB
  _Float16* Wqkvt = (_Float16*)(ws + 16777216);    // 3072x2048      12.58 MB
  _Float16* Wot   = (_Float16*)(ws + 29360128);    // 2048x2048       8.39 MB
  _Float16* qkv   = (_Float16*)(ws + 37748736);    // 4096x3072      25.17 MB
  _Float16* Qr    = (_Float16*)(ws + 62914560);    // 2x16x2048x128  16.78 MB
  _Float16* Kr    = (_Float16*)(ws + 79691776);    // 2x4x2048x128    4.19 MB
  _Float16* Vr    = (_Float16*)(ws + 83886080);    // 2x4x2048x128    4.19 MB
  _Float16* Ao    = (_Float16*)(ws + 88080384);    // 4096x2048      16.78 MB
                                                   // total 100 MB

  k_f32_to_f16<<<dim3(8192), dim3(256), 0, stream>>>(hidden, Xb, 2097152);
  k_transpose_f32_f16<<<dim3(64, 64), dim3(256), 0, stream>>>(Wq, Wqkvt, 2048, 0, 2048);
  k_transpose_f32_f16<<<dim3(64, 16), dim3(256), 0, stream>>>(Wk, Wqkvt, 512, 2048, 2048);
  k_transpose_f32_f16<<<dim3(64, 16), dim3(256), 0, stream>>>(Wv, Wqkvt, 512, 2560, 2048);
  k_transpose_f32_f16<<<dim3(64, 64), dim3(256), 0, stream>>>(Wo, Wot, 2048, 0, 2048);
  k_gemm<true><<<dim3(32, 24), dim3(256), 0, stream>>>(Xb, Wqkvt, (void*)qkv, 4096, 3072, 2048);
  k_normrope<<<dim3(4096, 6), dim3(256), 0, stream>>>(qkv, q_scale, k_scale, Qr, Kr, Vr);
  k_attn<<<dim3(32, 32), dim3(256), 0, stream>>>(Qr, Kr, Vr, Ao);
  k_gemm<false><<<dim3(32, 16), dim3(256), 0, stream>>>(Ao, Wot, d_out, 4096, 2048, 2048);
}

// Round 2
// 290.234 us; speedup vs baseline: 1.1216x; 1.1216x over previous
//
#include <hip/hip_runtime.h>
#include <stdint.h>

#define BB 2
#define SS 2048
#define MM 2048
#define NQ 16
#define NKV 4
#define HH 128
#define KVB 64

typedef __attribute__((ext_vector_type(4))) float f32x4;
typedef _Float16 f16x8 __attribute__((ext_vector_type(8)));
typedef _Float16 f16x4 __attribute__((ext_vector_type(4)));

__device__ __forceinline__ void gll16(const _Float16* g, _Float16* l) {
  __builtin_amdgcn_global_load_lds(
      (__attribute__((address_space(1))) void*)g,
      (__attribute__((address_space(3))) void*)l, 16, 0, 0);
}

// ---------------- fp32 -> fp16 convert (vectorized) ----------------
__global__ __launch_bounds__(256) void k_f32_to_f16(const float* __restrict__ in,
                                                    _Float16* __restrict__ out, int n4) {
  int i = blockIdx.x * 256 + threadIdx.x;
  if (i >= n4) return;
  float4 v = ((const float4*)in)[i];
  f16x4 o = { (_Float16)v.x, (_Float16)v.y, (_Float16)v.z, (_Float16)v.w };
  ((f16x4*)out)[i] = o;
}

// ------------- tiled transpose: in[K][N] f32 -> out[(n+n_off)][k] f16 -------------
__global__ __launch_bounds__(256) void k_transpose_f32_f16(
    const float* __restrict__ in, _Float16* __restrict__ out,
    int N_in, int n_off, int ldout) {
  __shared__ float tile[32][33];
  const int k0 = blockIdx.x * 32;
  const int n0 = blockIdx.y * 32;
  const int tx = threadIdx.x & 31;
  const int ty = threadIdx.x >> 5;
  #pragma unroll
  for (int r = ty; r < 32; r += 8)
    tile[r][tx] = in[(size_t)(k0 + r) * N_in + n0 + tx];
  __syncthreads();
  #pragma unroll
  for (int r = ty; r < 32; r += 8)
    out[(size_t)(n0 + r + n_off) * ldout + k0 + tx] = (_Float16)tile[tx][r];
}

// ------------- V transpose: qkv[b*S+s][2560+hv*128+h] -> VtG[(b*NKV+hv)*H+h][s] -------------
__global__ __launch_bounds__(256) void k_vtrans(const _Float16* __restrict__ qkv,
                                                _Float16* __restrict__ VtG) {
  __shared__ _Float16 tile[32][33];
  const int s0 = blockIdx.x * 32;
  const int z = blockIdx.y;        // (b*NKV+hv)*4 + h0/32
  const int h0 = (z & 3) * 32;
  const int bv = z >> 2;           // b*NKV+hv
  const int b = bv >> 2;
  const int hv = bv & 3;
  const int tx = threadIdx.x & 31;
  const int ty = threadIdx.x >> 5;
  #pragma unroll
  for (int r = ty; r < 32; r += 8)
    tile[r][tx] = qkv[(size_t)(b * SS + s0 + r) * 3072 + 2560 + hv * 128 + h0 + tx];
  __syncthreads();
  #pragma unroll
  for (int r = ty; r < 32; r += 8)
    VtG[((size_t)bv * HH + h0 + r) * SS + s0 + tx] = tile[tx][r];
}

// ---------------- 128x128 MFMA GEMM: C[M][N] = A[M][K] * Bt[N][K]^T ----------------
template <bool F16OUT>
__global__ __launch_bounds__(256) void k_gemm(
    const _Float16* __restrict__ A, const _Float16* __restrict__ Bt,
    void* __restrict__ Cout, int Mrows, int N, int K) {
  __shared__ _Float16 As[128 * 32];
  __shared__ _Float16 Bs[128 * 32];
  const int bm = blockIdx.x * 128;
  const int bn = blockIdx.y * 128;
  const int w = threadIdx.x >> 6;
  const int l = threadIdx.x & 63;
  const int lg = l >> 4, lr = l & 15;
  const int wr = w >> 1, wc = w & 1;

  f32x4 acc[4][4] = {};

  const _Float16* gA = A + (size_t)(bm + w * 32 + (l >> 2)) * K + (l & 3) * 8;
  const _Float16* gB = Bt + (size_t)(bn + w * 32 + (l >> 2)) * K + (l & 3) * 8;
  _Float16* lA = As + w * 32 * 32;
  _Float16* lB = Bs + w * 32 * 32;
  const size_t g16 = (size_t)16 * K;

  for (int k0 = 0; k0 < K; k0 += 32) {
    gll16(gA, lA);
    gll16(gA + g16, lA + 16 * 32);
    gll16(gB, lB);
    gll16(gB + g16, lB + 16 * 32);
    gA += 32; gB += 32;
    __syncthreads();
    f16x8 af[4], bfr[4];
    #pragma unroll
    for (int mt = 0; mt < 4; mt++)
      af[mt] = *(const f16x8*)(As + (wr * 64 + mt * 16 + lr) * 32 + lg * 8);
    #pragma unroll
    for (int ntb = 0; ntb < 4; ntb++)
      bfr[ntb] = *(const f16x8*)(Bs + (wc * 64 + ntb * 16 + lr) * 32 + lg * 8);
    #pragma unroll
    for (int mt = 0; mt < 4; mt++)
      #pragma unroll
      for (int ntb = 0; ntb < 4; ntb++)
        acc[mt][ntb] = __builtin_amdgcn_mfma_f32_16x16x32_f16(af[mt], bfr[ntb], acc[mt][ntb], 0, 0, 0);
    __syncthreads();
  }
  #pragma unroll
  for (int mt = 0; mt < 4; mt++) {
    #pragma unroll
    for (int i = 0; i < 4; i++) {
      const int row = bm + wr * 64 + mt * 16 + lg * 4 + i;
      #pragma unroll
      for (int ntb = 0; ntb < 4; ntb++) {
        const int col = bn + wc * 64 + ntb * 16 + lr;
        if (F16OUT)
          ((_Float16*)Cout)[(size_t)row * N + col] = (_Float16)acc[mt][ntb][i];
        else
          ((float*)Cout)[(size_t)row * N + col] = acc[mt][ntb][i];
      }
    }
  }
}

// ---------------- fused RMSNorm + RoPE + scatter (Q, K only) ----------------
__global__ __launch_bounds__(256) void k_normrope(
    const _Float16* __restrict__ qkv,
    const float* __restrict__ q_scale, const float* __restrict__ k_scale,
    _Float16* __restrict__ Qr, _Float16* __restrict__ Kr) {
  const int row = blockIdx.x;          // b*S + s
  const int b = row >> 11;
  const int s = row & 2047;
  const int hh = blockIdx.y * 4 + (threadIdx.x >> 6);   // 0..19
  const int l = threadIdx.x & 63;
  const _Float16* src = qkv + (size_t)row * 3072 + hh * 128 + l * 2;
  float x0 = (float)src[0];
  float x1 = (float)src[1];
  float ssum = x0 * x0 + x1 * x1;
  #pragma unroll
  for (int d = 1; d < 64; d <<= 1) ssum += __shfl_xor(ssum, d);
  const float rstd = rsqrtf(ssum * (1.f / 128.f) + 1e-6f);
  const float* scl = (hh < 16) ? q_scale : k_scale;
  x0 *= rstd * scl[2 * l];
  x1 *= rstd * scl[2 * l + 1];
  const float y0 = __shfl_xor(x0, 32);
  const float y1 = __shfl_xor(x1, 32);
  const int j0 = (2 * l) & 63;
  const float kLog = 0.20762050593046014f;  // log2(10000)/64
  const float f0 = (float)s * exp2f(-(float)j0 * kLog);
  const float f1 = (float)s * exp2f(-(float)(j0 + 1) * kLog);
  const float c0 = cosf(f0), s0 = sinf(f0);
  const float c1 = cosf(f1), s1 = sinf(f1);
  float r0, r1;
  if (l < 32) { r0 = x0 * c0 - y0 * s0; r1 = x1 * c1 - y1 * s1; }
  else        { r0 = x0 * c0 + y0 * s0; r1 = x1 * c1 + y1 * s1; }
  if (hh < 16) {
    _Float16* dst = Qr + ((size_t)(b * NQ + hh) * SS + s) * HH + 2 * l;
    dst[0] = (_Float16)r0; dst[1] = (_Float16)r1;
  } else {
    _Float16* dst = Kr + ((size_t)(b * NKV + (hh - 16)) * SS + s) * HH + 2 * l;
    dst[0] = (_Float16)r0; dst[1] = (_Float16)r1;
  }
}

// ---------------- causal GQA flash attention (8 waves, QBLK=128, dbuf K/V) ----------------
// Qr: [B][NQ][S][H], Kr: [B][NKV][S][H], VtG: [B][NKV][H][S], Ao: [B][S][NQ][H]
__global__ __launch_bounds__(512, 4) void k_attn(
    const _Float16* __restrict__ Qr, const _Float16* __restrict__ Kr,
    const _Float16* __restrict__ VtG, _Float16* __restrict__ Ao) {
  __shared__ _Float16 Ks[2][64 * 128];   // linear, XOR-swizzled content
  __shared__ _Float16 Vs[2][128 * 64];   // V^T tile, linear, XOR-swizzled content
  __shared__ _Float16 Ps[8][16 * 64];    // per-wave P, XOR-swizzled

  const int tid = threadIdx.x;
  const int w = tid >> 6;
  const int l = tid & 63;
  const int lg = l >> 4, lr = l & 15;
  const int bu = blockIdx.x;
  const int b = bu >> 4, u = bu & 15;
  const int kvh = u >> 2;
  const int qt = 15 - blockIdx.y;        // heavy q-tiles dispatched first
  const int q0 = qt * 128;
  const int ntiles = 2 * qt + 2;
  const float inv_norm = 0.08838834764831845f;  // 1/sqrt(128)

  const _Float16* Kbase = Kr + (size_t)(b * NKV + kvh) * SS * HH;
  const _Float16* Vbase = VtG + (size_t)(b * NKV + kvh) * HH * SS;

  // Q fragments (A-operand): rows q0 + w*16 + lr
  f16x8 qf[4];
  {
    const _Float16* qp = Qr + ((size_t)(b * NQ + u) * SS + q0 + w * 16 + lr) * HH + lg * 8;
    #pragma unroll
    for (int hs = 0; hs < 4; hs++) qf[hs] = *(const f16x8*)(qp + hs * 32);
  }

  f32x4 acc[8] = {};
  float mrow[4], lrow[4];
  #pragma unroll
  for (int i = 0; i < 4; i++) { mrow[i] = -1e30f; lrow[i] = 0.f; }

  char* Pw = (char*)&Ps[w][0];

  // staging: pre-swizzled global source -> linear LDS (rule #21)
  auto stage = [&](int buf, int t) {
    const int kv0 = t * KVB;
    #pragma unroll
    for (int i = 0; i < 2; i++) {
      const int n = i * 512 + tid;
      {  // K tile: 64 rows x 256B
        const int row = n >> 4;
        const int s8 = (n & 15) ^ (row & 7);
        gll16(Kbase + (size_t)(kv0 + row) * HH + s8 * 8,
              &Ks[buf][(size_t)(i * 512 + w * 64) * 8]);
      }
      {  // V^T tile: 128 rows x 128B
        const int row = n >> 3;
        const int s8 = (n & 7) ^ (row & 7);
        gll16(Vbase + (size_t)row * SS + kv0 + s8 * 8,
              &Vs[buf][(size_t)(i * 512 + w * 64) * 8]);
      }
    }
  };

  int cur = 0;
  stage(0, 0);
  __syncthreads();

  for (int t = 0; t < ntiles; t++) {
    if (t + 1 < ntiles) stage(cur ^ 1, t + 1);
    const int kv0 = t * KVB;
    const bool active = (kv0 <= q0 + w * 16 + 15);
    if (active) {
      const char* Kb = (const char*)&Ks[cur][0];
      const char* Vb = (const char*)&Vs[cur][0];

      // QK^T
      f32x4 sc[4] = {};
      __builtin_amdgcn_s_setprio(1);
      #pragma unroll
      for (int hs = 0; hs < 4; hs++)
        #pragma unroll
        for (int kt_ = 0; kt_ < 4; kt_++) {
          const int krow = kt_ * 16 + lr;
          f16x8 kf = *(const f16x8*)(Kb + krow * 256 + ((hs * 64 + lg * 16) ^ ((krow & 7) << 4)));
          sc[kt_] = __builtin_amdgcn_mfma_f32_16x16x32_f16(qf[hs], kf, sc[kt_], 0, 0, 0);
        }
      __builtin_amdgcn_s_setprio(0);

      // mask (diagonal tiles only) + scale + online softmax
      float p[4][4], tmax[4];
      const int qa_base = q0 + w * 16 + lg * 4;
      const bool domask = (kv0 + KVB - 1 > q0 + w * 16);
      #pragma unroll
      for (int i = 0; i < 4; i++) tmax[i] = -1e30f;
      #pragma unroll
      for (int kt_ = 0; kt_ < 4; kt_++) {
        const int ka = kv0 + kt_ * 16 + lr;
        #pragma unroll
        for (int i = 0; i < 4; i++) {
          float sv = sc[kt_][i] * inv_norm;
          if (domask && ka > qa_base + i) sv = -1e9f;
          p[kt_][i] = sv;
          tmax[i] = fmaxf(tmax[i], sv);
        }
      }
      #pragma unroll
      for (int i = 0; i < 4; i++)
        #pragma unroll
        for (int d = 1; d < 16; d <<= 1)
          tmax[i] = fmaxf(tmax[i], __shfl_xor(tmax[i], d));

      float corr[4], psum[4];
      #pragma unroll
      for (int i = 0; i < 4; i++) {
        const float mnew = fmaxf(mrow[i], tmax[i]);
        corr[i] = __expf(mrow[i] - mnew);
        mrow[i] = mnew;
        float acc_s = 0.f;
        #pragma unroll
        for (int kt_ = 0; kt_ < 4; kt_++) {
          const float e = __expf(p[kt_][i] - mnew);
          p[kt_][i] = e;
          acc_s += e;
        }
        psum[i] = acc_s;
      }
      #pragma unroll
      for (int i = 0; i < 4; i++) {
        #pragma unroll
        for (int d = 1; d < 16; d <<= 1) psum[i] += __shfl_xor(psum[i], d);
        lrow[i] = lrow[i] * corr[i] + psum[i];
      }
      #pragma unroll
      for (int ht = 0; ht < 8; ht++)
        #pragma unroll
        for (int i = 0; i < 4; i++) acc[ht][i] *= corr[i];

      // P -> per-wave swizzled LDS (row = lg*4+i, col = kt_*16+lr)
      #pragma unroll
      for (int kt_ = 0; kt_ < 4; kt_++)
        #pragma unroll
        for (int i = 0; i < 4; i++) {
          const int prow = lg * 4 + i;
          *(_Float16*)(Pw + prow * 128 + ((((kt_ * 16 + lr) * 2)) ^ ((prow & 7) << 4))) =
              (_Float16)p[kt_][i];
        }

      // PV: A = P (row=lr), B = V^T (col h = lr)
      f16x8 pf0 = *(const f16x8*)(Pw + lr * 128 + ((lg * 16) ^ ((lr & 7) << 4)));
      f16x8 pf1 = *(const f16x8*)(Pw + lr * 128 + ((64 + lg * 16) ^ ((lr & 7) << 4)));
      __builtin_amdgcn_s_setprio(1);
      #pragma unroll
      for (int ht = 0; ht < 8; ht++) {
        const int vrow = ht * 16 + lr;
        f16x8 vf0 = *(const f16x8*)(Vb + vrow * 128 + ((lg * 16) ^ ((vrow & 7) << 4)));
        acc[ht] = __builtin_amdgcn_mfma_f32_16x16x32_f16(pf0, vf0, acc[ht], 0, 0, 0);
        f16x8 vf1 = *(const f16x8*)(Vb + vrow * 128 + ((64 + lg * 16) ^ ((vrow & 7) << 4)));
        acc[ht] = __builtin_amdgcn_mfma_f32_16x16x32_f16(pf1, vf1, acc[ht], 0, 0, 0);
      }
      __builtin_amdgcn_s_setprio(0);
    }
    __syncthreads();   // drains vmcnt (staged t+1 complete) + all waves done with buf
    cur ^= 1;
  }

  float inv[4];
  #pragma unroll
  for (int i = 0; i < 4; i++) inv[i] = 1.f / lrow[i];
  #pragma unroll
  for (int ht = 0; ht < 8; ht++)
    #pragma unroll
    for (int i = 0; i < 4; i++) {
      const int qa = q0 + w * 16 + lg * 4 + i;
      Ao[((size_t)(b * SS + qa) * NQ + u) * HH + ht * 16 + lr] = (_Float16)(acc[ht][i] * inv[i]);
    }
}

// ---------------- launcher ----------------
extern "C" void kernel_launch(void* const* d_in, const int* in_sizes, int n_in,
                              void* d_out, int out_size, void* d_ws, size_t ws_size,
                              hipStream_t stream) {
  const float* hidden = (const float*)d_in[0];
  const float* Wq = (const float*)d_in[2];
  const float* Wk = (const float*)d_in[3];
  const float* Wv = (const float*)d_in[4];
  const float* Wo = (const float*)d_in[5];
  const float* q_scale = (const float*)d_in[6];
  const float* k_scale = (const float*)d_in[7];

  char* ws = (char*)d_ws;
  _Float16* Xb    = (_Float16*)(ws);               // 4096x2048      16.78 MB
  _Float16* Wqkvt = (_Float16*)(ws + 16777216);    // 3072x2048      12.58 MB
  _Float16* Wot   = (_Float16*)(ws + 29360128);    // 2048x2048       8.39 MB
  _Float16* qkv   = (_Float16*)(ws + 37748736);    // 4096x3072      25.17 MB
  _Float16* Qr    = (_Float16*)(ws + 62914560);    // 2x16x2048x128  16.78 MB
  _Float16* Kr    = (_Float16*)(ws + 79691776);    // 2x4x2048x128    4.19 MB
  _Float16* VtG   = (_Float16*)(ws + 83886080);    // 2x4x128x2048    4.19 MB
  _Float16* Ao    = (_Float16*)(ws + 88080384);    // 4096x2048      16.78 MB

  k_f32_to_f16<<<dim3(8192), dim3(256), 0, stream>>>(hidden, Xb, 2097152);
  k_transpose_f32_f16<<<dim3(64, 64), dim3(256), 0, stream>>>(Wq, Wqkvt, 2048, 0, 2048);
  k_transpose_f32_f16<<<dim3(64, 16), dim3(256), 0, stream>>>(Wk, Wqkvt, 512, 2048, 2048);
  k_transpose_f32_f16<<<dim3(64, 16), dim3(256), 0, stream>>>(Wv, Wqkvt, 512, 2560, 2048);
  k_transpose_f32_f16<<<dim3(64, 64), dim3(256), 0, stream>>>(Wo, Wot, 2048, 0, 2048);
  k_gemm<true><<<dim3(32, 24), dim3(256), 0, stream>>>(Xb, Wqkvt, (void*)qkv, 4096, 3072, 2048);
  k_normrope<<<dim3(4096, 5), dim3(256), 0, stream>>>(qkv, q_scale, k_scale, Qr, Kr);
  k_vtrans<<<dim3(64, 32), dim3(256), 0, stream>>>(qkv, VtG);
  k_attn<<<dim3(32, 16), dim3(512), 0, stream>>>(Qr, Kr, VtG, Ao);
  k_gemm<false><<<dim3(32, 16), dim3(256), 0, stream>>>(Ao, Wot, d_out, 4096, 2048, 2048);
}

// Round 3
// 261.696 us; speedup vs baseline: 1.2439x; 1.1091x over previous
//
#include <hip/hip_runtime.h>
#include <stdint.h>

#define BB 2
#define SS 2048
#define MM 2048
#define NQ 16
#define NKV 4
#define HH 128
#define KVB 64

typedef __attribute__((ext_vector_type(4))) float f32x4;
typedef __attribute__((ext_vector_type(16))) float f32x16;
typedef _Float16 f16x8 __attribute__((ext_vector_type(8)));
typedef _Float16 f16x4 __attribute__((ext_vector_type(4)));
typedef _Float16 f16x2 __attribute__((ext_vector_type(2)));
typedef unsigned int uint4v __attribute__((ext_vector_type(4)));

__device__ __forceinline__ void gll16(const _Float16* g, _Float16* l) {
  __builtin_amdgcn_global_load_lds(
      (__attribute__((address_space(1))) void*)g,
      (__attribute__((address_space(3))) void*)l, 16, 0, 0);
}

// ---------------- fp32 -> fp16 convert (vectorized) ----------------
__global__ __launch_bounds__(256) void k_f32_to_f16(const float* __restrict__ in,
                                                    _Float16* __restrict__ out, int n4) {
  int i = blockIdx.x * 256 + threadIdx.x;
  if (i >= n4) return;
  float4 v = ((const float4*)in)[i];
  f16x4 o = { (_Float16)v.x, (_Float16)v.y, (_Float16)v.z, (_Float16)v.w };
  ((f16x4*)out)[i] = o;
}

// ------------- tiled transpose: in[K][N] f32 -> out[(n+n_off)][k] f16 -------------
__global__ __launch_bounds__(256) void k_transpose_f32_f16(
    const float* __restrict__ in, _Float16* __restrict__ out,
    int N_in, int n_off, int ldout) {
  __shared__ float tile[32][33];
  const int k0 = blockIdx.x * 32;
  const int n0 = blockIdx.y * 32;
  const int tx = threadIdx.x & 31;
  const int ty = threadIdx.x >> 5;
  #pragma unroll
  for (int r = ty; r < 32; r += 8)
    tile[r][tx] = in[(size_t)(k0 + r) * N_in + n0 + tx];
  __syncthreads();
  #pragma unroll
  for (int r = ty; r < 32; r += 8)
    out[(size_t)(n0 + r + n_off) * ldout + k0 + tx] = (_Float16)tile[tx][r];
}

// ------------- V transpose: qkv[b*S+s][2560+hv*128+h] -> VtG[(b*NKV+hv)*H+h][s] -------------
__global__ __launch_bounds__(256) void k_vtrans(const _Float16* __restrict__ qkv,
                                                _Float16* __restrict__ VtG) {
  __shared__ _Float16 tile[32][33];
  const int s0 = blockIdx.x * 32;
  const int z = blockIdx.y;        // (b*NKV+hv)*4 + h0/32
  const int h0 = (z & 3) * 32;
  const int bv = z >> 2;           // b*NKV+hv
  const int b = bv >> 2;
  const int hv = bv & 3;
  const int tx = threadIdx.x & 31;
  const int ty = threadIdx.x >> 5;
  #pragma unroll
  for (int r = ty; r < 32; r += 8)
    tile[r][tx] = qkv[(size_t)(b * SS + s0 + r) * 3072 + 2560 + hv * 128 + h0 + tx];
  __syncthreads();
  #pragma unroll
  for (int r = ty; r < 32; r += 8)
    VtG[((size_t)bv * HH + h0 + r) * SS + s0 + tx] = tile[tx][r];
}

// ------------- score bound: M2 = log2e * max|q_scale| * max|k_scale| -------------
__global__ void k_bound(const float* __restrict__ qs, const float* __restrict__ ks,
                        float* __restrict__ out) {
  const int l = threadIdx.x;
  float a = fmaxf(fabsf(qs[l]), fabsf(qs[l + 64]));
  float bb = fmaxf(fabsf(ks[l]), fabsf(ks[l + 64]));
  #pragma unroll
  for (int d = 1; d < 64; d <<= 1) {
    a = fmaxf(a, __shfl_xor(a, d));
    bb = fmaxf(bb, __shfl_xor(bb, d));
  }
  if (l == 0) out[0] = 1.4426950408889634f * a * bb;
}

// ---------------- 128x128 MFMA GEMM: C[M][N] = A[M][K] * Bt[N][K]^T ----------------
template <bool F16OUT>
__global__ __launch_bounds__(256) void k_gemm(
    const _Float16* __restrict__ A, const _Float16* __restrict__ Bt,
    void* __restrict__ Cout, int Mrows, int N, int K) {
  __shared__ _Float16 As[128 * 32];
  __shared__ _Float16 Bs[128 * 32];
  const int bm = blockIdx.x * 128;
  const int bn = blockIdx.y * 128;
  const int w = threadIdx.x >> 6;
  const int l = threadIdx.x & 63;
  const int lg = l >> 4, lr = l & 15;
  const int wr = w >> 1, wc = w & 1;

  f32x4 acc[4][4] = {};

  const _Float16* gA = A + (size_t)(bm + w * 32 + (l >> 2)) * K + (l & 3) * 8;
  const _Float16* gB = Bt + (size_t)(bn + w * 32 + (l >> 2)) * K + (l & 3) * 8;
  _Float16* lA = As + w * 32 * 32;
  _Float16* lB = Bs + w * 32 * 32;
  const size_t g16 = (size_t)16 * K;

  for (int k0 = 0; k0 < K; k0 += 32) {
    gll16(gA, lA);
    gll16(gA + g16, lA + 16 * 32);
    gll16(gB, lB);
    gll16(gB + g16, lB + 16 * 32);
    gA += 32; gB += 32;
    __syncthreads();
    f16x8 af[4], bfr[4];
    #pragma unroll
    for (int mt = 0; mt < 4; mt++)
      af[mt] = *(const f16x8*)(As + (wr * 64 + mt * 16 + lr) * 32 + lg * 8);
    #pragma unroll
    for (int ntb = 0; ntb < 4; ntb++)
      bfr[ntb] = *(const f16x8*)(Bs + (wc * 64 + ntb * 16 + lr) * 32 + lg * 8);
    #pragma unroll
    for (int mt = 0; mt < 4; mt++)
      #pragma unroll
      for (int ntb = 0; ntb < 4; ntb++)
        acc[mt][ntb] = __builtin_amdgcn_mfma_f32_16x16x32_f16(af[mt], bfr[ntb], acc[mt][ntb], 0, 0, 0);
    __syncthreads();
  }
  #pragma unroll
  for (int mt = 0; mt < 4; mt++) {
    #pragma unroll
    for (int i = 0; i < 4; i++) {
      const int row = bm + wr * 64 + mt * 16 + lg * 4 + i;
      #pragma unroll
      for (int ntb = 0; ntb < 4; ntb++) {
        const int col = bn + wc * 64 + ntb * 16 + lr;
        if (F16OUT)
          ((_Float16*)Cout)[(size_t)row * N + col] = (_Float16)acc[mt][ntb][i];
        else
          ((float*)Cout)[(size_t)row * N + col] = acc[mt][ntb][i];
      }
    }
  }
}

// ---------------- fused RMSNorm + RoPE + scatter (Q, K only) ----------------
__global__ __launch_bounds__(256) void k_normrope(
    const _Float16* __restrict__ qkv,
    const float* __restrict__ q_scale, const float* __restrict__ k_scale,
    _Float16* __restrict__ Qr, _Float16* __restrict__ Kr) {
  const int row = blockIdx.x;          // b*S + s
  const int b = row >> 11;
  const int s = row & 2047;
  const int hh = blockIdx.y * 4 + (threadIdx.x >> 6);   // 0..19
  const int l = threadIdx.x & 63;
  const _Float16* src = qkv + (size_t)row * 3072 + hh * 128 + l * 2;
  float x0 = (float)src[0];
  float x1 = (float)src[1];
  float ssum = x0 * x0 + x1 * x1;
  #pragma unroll
  for (int d = 1; d < 64; d <<= 1) ssum += __shfl_xor(ssum, d);
  const float rstd = rsqrtf(ssum * (1.f / 128.f) + 1e-6f);
  const float* scl = (hh < 16) ? q_scale : k_scale;
  x0 *= rstd * scl[2 * l];
  x1 *= rstd * scl[2 * l + 1];
  const float y0 = __shfl_xor(x0, 32);
  const float y1 = __shfl_xor(x1, 32);
  const int j0 = (2 * l) & 63;
  const float kLog = 0.20762050593046014f;  // log2(10000)/64
  const float f0 = (float)s * exp2f(-(float)j0 * kLog);
  const float f1 = (float)s * exp2f(-(float)(j0 + 1) * kLog);
  const float c0 = cosf(f0), s0 = sinf(f0);
  const float c1 = cosf(f1), s1 = sinf(f1);
  float r0, r1;
  if (l < 32) { r0 = x0 * c0 - y0 * s0; r1 = x1 * c1 - y1 * s1; }
  else        { r0 = x0 * c0 + y0 * s0; r1 = x1 * c1 + y1 * s1; }
  if (hh < 16) {
    _Float16* dst = Qr + ((size_t)(b * NQ + hh) * SS + s) * HH + 2 * l;
    dst[0] = (_Float16)r0; dst[1] = (_Float16)r1;
  } else {
    _Float16* dst = Kr + ((size_t)(b * NKV + (hh - 16)) * SS + s) * HH + 2 * l;
    dst[0] = (_Float16)r0; dst[1] = (_Float16)r1;
  }
}

// ---------------- causal GQA flash attention: swapped-QK, in-register softmax ----------------
// Qr: [B][NQ][S][H], Kr: [B][NKV][S][H], VtG: [B][NKV][H][S], Ao: [B][S][NQ][H]
// 4 waves x 32 q-rows = 128 q/block. KVB=64 dbuf. Static softmax max from bound[].
__global__ __launch_bounds__(256, 2) void k_attn(
    const _Float16* __restrict__ Qr, const _Float16* __restrict__ Kr,
    const _Float16* __restrict__ VtG, const float* __restrict__ bound,
    _Float16* __restrict__ Ao) {
  __shared__ _Float16 Ks[2][64 * 128];    // K tile, XOR-swizzled content, linear layout
  __shared__ _Float16 Vs[2][128 * 64];    // V^T tile, XOR-swizzled content

  const int tid = threadIdx.x;
  const int w = tid >> 6;
  const int l = tid & 63;
  const int l31 = l & 31;
  const int hi = l >> 5;
  const int sw7 = (l31 & 7) << 4;        // read-side XOR (row&7 pattern, rows stride 32)
  const int bu = blockIdx.x;
  const int b = bu >> 4, u = bu & 15;
  const int kvh = u >> 2;
  const int qt = 15 - (int)blockIdx.y;   // heavy strips dispatched first
  const int q0 = qt * 128;
  const int nt = 2 * qt + 2;
  const float M2 = bound[0];
  const float K2 = 0.12752982260735795f; // log2(e)/sqrt(128)

  const _Float16* Kbase = Kr + (size_t)(b * NKV + kvh) * SS * HH;
  const _Float16* Vbase = VtG + (size_t)(b * NKV + kvh) * HH * SS;

  // Q fragments (B-operand of swapped QK^T): lane holds Q[q0+w*32+l31][hs*16+hi*8 ..+7]
  f16x8 qf[8];
  {
    const _Float16* qp = Qr + ((size_t)(b * NQ + u) * SS + q0 + w * 32 + l31) * HH + hi * 8;
    #pragma unroll
    for (int hs = 0; hs < 8; hs++) {
      qf[hs] = *(const f16x8*)(qp + hs * 16);
      qf[hs] *= (_Float16)K2;            // fold 1/sqrt(H) * log2e into Q
    }
  }

  f32x16 acc0 = {}, acc1 = {}, acc2 = {}, acc3 = {};
  float psum = 0.f;

  auto stage = [&](int buf, int t) {
    const int kv0 = t * KVB;
    #pragma unroll
    for (int it = 0; it < 4; it++) {
      const int n = it * 256 + tid;
      {  // K tile: 64 rows x 256B (16 chunks)
        const int row = n >> 4, c = n & 15;
        const int cs = c ^ (row & 7);
        gll16(Kbase + (size_t)(kv0 + row) * HH + cs * 8,
              &Ks[buf][(size_t)(it * 256 + w * 64) * 8]);
      }
      {  // V^T tile: 128 rows x 128B (8 chunks)
        const int row = n >> 3, c = n & 7;
        const int cs = c ^ (row & 7);
        gll16(Vbase + (size_t)row * SS + kv0 + cs * 8,
              &Vs[buf][(size_t)(it * 256 + w * 64) * 8]);
      }
    }
  };

  int buf = 0;
  stage(0, 0);
  __syncthreads();

  const int qwb = q0 + w * 32;           // wave's first q-row
  const int qlane = qwb + l31;           // lane's q-row

  for (int t = 0; t < nt; t++) {
    if (t + 1 < nt) stage(buf ^ 1, t + 1);
    const int kv0 = t * KVB;
    if (kv0 <= qwb + 31) {
      const char* Kb = (const char*)&Ks[buf][0];
      const char* Vb = (const char*)&Vs[buf][0];

      // ---- QK^T (swapped): S[k][q], lane = q-col ----
      f32x16 S0 = {}, S1 = {};
      __builtin_amdgcn_s_setprio(1);
      #pragma unroll
      for (int hs = 0; hs < 8; hs++) {
        const int ch = hs * 2 + hi;
        f16x8 k0 = *(const f16x8*)(Kb + l31 * 256 + ((ch << 4) ^ sw7));
        f16x8 k1 = *(const f16x8*)(Kb + (32 + l31) * 256 + ((ch << 4) ^ sw7));
        S0 = __builtin_amdgcn_mfma_f32_32x32x16_f16(k0, qf[hs], S0, 0, 0, 0);
        S1 = __builtin_amdgcn_mfma_f32_32x32x16_f16(k1, qf[hs], S1, 0, 0, 0);
      }
      __builtin_amdgcn_s_setprio(0);

      // ---- softmax numerator: p = 2^(s - M2); causal mask; lane-local sum ----
      const bool domask = (kv0 + 63 > qwb);
      float p0[16], p1[16];
      #pragma unroll
      for (int r = 0; r < 16; r++) {
        const int cr = (r & 3) + 8 * (r >> 2) + 4 * hi;  // k-row of reg r
        float e0 = exp2f(S0[r] - M2);
        float e1 = exp2f(S1[r] - M2);
        if (domask) {
          if (kv0 + cr > qlane) e0 = 0.f;
          if (kv0 + 32 + cr > qlane) e1 = 0.f;
        }
        p0[r] = e0; p1[r] = e1;
        psum += e0 + e1;
      }

      // ---- P -> fp16 A-frags in-register (pack + cross-half swap) ----
      unsigned int pkv[4][4];  // [ts*2 + (a|b)][pair]
      #pragma unroll
      for (int g = 0; g < 4; g++) {
        f16x2 ha = { (_Float16)p0[2 * g], (_Float16)p0[2 * g + 1] };
        f16x2 hb = { (_Float16)p0[8 + 2 * g], (_Float16)p0[9 + 2 * g] };
        f16x2 hc = { (_Float16)p1[2 * g], (_Float16)p1[2 * g + 1] };
        f16x2 hd = { (_Float16)p1[8 + 2 * g], (_Float16)p1[9 + 2 * g] };
        pkv[0][g] = __builtin_bit_cast(unsigned int, ha);
        pkv[1][g] = __builtin_bit_cast(unsigned int, hb);
        pkv[2][g] = __builtin_bit_cast(unsigned int, hc);
        pkv[3][g] = __builtin_bit_cast(unsigned int, hd);
      }
      f16x8 pa[4];
      #pragma unroll
      for (int ks = 0; ks < 4; ks++) {
        unsigned int a0 = pkv[ks][0], a1 = pkv[ks][1], a2 = pkv[ks][2], a3 = pkv[ks][3];
        unsigned int x0 = (unsigned int)__shfl_xor((int)a0, 32);
        unsigned int x1 = (unsigned int)__shfl_xor((int)a1, 32);
        unsigned int x2 = (unsigned int)__shfl_xor((int)a2, 32);
        unsigned int x3 = (unsigned int)__shfl_xor((int)a3, 32);
        uint4v dv;
        dv.x = hi ? x2 : a0;   // k pairs (hi*8 + 0,1)
        dv.y = hi ? x3 : a1;   // (hi*8 + 2,3)
        dv.z = hi ? a2 : x0;   // (hi*8 + 4,5)
        dv.w = hi ? a3 : x1;   // (hi*8 + 6,7)
        pa[ks] = __builtin_bit_cast(f16x8, dv);
      }

      // ---- PV: acc[q][h] += P * V ----
      __builtin_amdgcn_s_setprio(1);
      #pragma unroll
      for (int ks = 0; ks < 4; ks++) {
        const int ch = ks * 2 + hi;
        f16x8 v0 = *(const f16x8*)(Vb + (0 * 32 + l31) * 128 + ((ch << 4) ^ sw7));
        acc0 = __builtin_amdgcn_mfma_f32_32x32x16_f16(pa[ks], v0, acc0, 0, 0, 0);
        f16x8 v1 = *(const f16x8*)(Vb + (1 * 32 + l31) * 128 + ((ch << 4) ^ sw7));
        acc1 = __builtin_amdgcn_mfma_f32_32x32x16_f16(pa[ks], v1, acc1, 0, 0, 0);
        f16x8 v2 = *(const f16x8*)(Vb + (2 * 32 + l31) * 128 + ((ch << 4) ^ sw7));
        acc2 = __builtin_amdgcn_mfma_f32_32x32x16_f16(pa[ks], v2, acc2, 0, 0, 0);
        f16x8 v3 = *(const f16x8*)(Vb + (3 * 32 + l31) * 128 + ((ch << 4) ^ sw7));
        acc3 = __builtin_amdgcn_mfma_f32_32x32x16_f16(pa[ks], v3, acc3, 0, 0, 0);
      }
      __builtin_amdgcn_s_setprio(0);
    }
    __syncthreads();
    buf ^= 1;
  }

  // ---- finalize: combine halves, divide, write ----
  const float tot = psum + __shfl_xor(psum, 32);
  const float inv = 1.f / tot;
  #pragma unroll
  for (int r = 0; r < 16; r++) {
    const int cr = (r & 3) + 8 * (r >> 2) + 4 * hi;
    const float ivr = __shfl(inv, cr);   // inv for q-row cr lives in lane cr
    _Float16* dst = Ao + ((size_t)(b * SS + q0 + w * 32 + cr)) * MM + u * HH + l31;
    dst[0]  = (_Float16)(acc0[r] * ivr);
    dst[32] = (_Float16)(acc1[r] * ivr);
    dst[64] = (_Float16)(acc2[r] * ivr);
    dst[96] = (_Float16)(acc3[r] * ivr);
  }
}

// ---------------- launcher ----------------
extern "C" void kernel_launch(void* const* d_in, const int* in_sizes, int n_in,
                              void* d_out, int out_size, void* d_ws, size_t ws_size,
                              hipStream_t stream) {
  const float* hidden = (const float*)d_in[0];
  const float* Wq = (const float*)d_in[2];
  const float* Wk = (const float*)d_in[3];
  const float* Wv = (const float*)d_in[4];
  const float* Wo = (const float*)d_in[5];
  const float* q_scale = (const float*)d_in[6];
  const float* k_scale = (const float*)d_in[7];

  char* ws = (char*)d_ws;
  _Float16* Xb    = (_Float16*)(ws);               // 4096x2048      16.78 MB
  _Float16* Wqkvt = (_Float16*)(ws + 16777216);    // 3072x2048      12.58 MB
  _Float16* Wot   = (_Float16*)(ws + 29360128);    // 2048x2048       8.39 MB
  _Float16* qkv   = (_Float16*)(ws + 37748736);    // 4096x3072      25.17 MB
  _Float16* Qr    = (_Float16*)(ws + 62914560);    // 2x16x2048x128  16.78 MB
  _Float16* Kr    = (_Float16*)(ws + 79691776);    // 2x4x2048x128    4.19 MB
  _Float16* VtG   = (_Float16*)(ws + 83886080);    // 2x4x128x2048    4.19 MB
  _Float16* Ao    = (_Float16*)(ws + 88080384);    // 4096x2048      16.78 MB
  float*    bnd   = (float*)(ws + 37748736);       // reuses dead qkv area (after vtrans)

  k_f32_to_f16<<<dim3(8192), dim3(256), 0, stream>>>(hidden, Xb, 2097152);
  k_transpose_f32_f16<<<dim3(64, 64), dim3(256), 0, stream>>>(Wq, Wqkvt, 2048, 0, 2048);
  k_transpose_f32_f16<<<dim3(64, 16), dim3(256), 0, stream>>>(Wk, Wqkvt, 512, 2048, 2048);
  k_transpose_f32_f16<<<dim3(64, 16), dim3(256), 0, stream>>>(Wv, Wqkvt, 512, 2560, 2048);
  k_transpose_f32_f16<<<dim3(64, 64), dim3(256), 0, stream>>>(Wo, Wot, 2048, 0, 2048);
  k_gemm<true><<<dim3(32, 24), dim3(256), 0, stream>>>(Xb, Wqkvt, (void*)qkv, 4096, 3072, 2048);
  k_normrope<<<dim3(4096, 5), dim3(256), 0, stream>>>(qkv, q_scale, k_scale, Qr, Kr);
  k_vtrans<<<dim3(64, 32), dim3(256), 0, stream>>>(qkv, VtG);
  k_bound<<<dim3(1), dim3(64), 0, stream>>>(q_scale, k_scale, bnd);
  k_attn<<<dim3(32, 16), dim3(256), 0, stream>>>(Qr, Kr, VtG, bnd, Ao);
  k_gemm<false><<<dim3(32, 16), dim3(256), 0, stream>>>(Ao, Wot, d_out, 4096, 2048, 2048);
}